// Round 27
// baseline (154.592 us; speedup 1.0000x reference)
//
#include <hip/hip_runtime.h>
#include <math.h>

#define CC 96
#define BB 512
#define TT 512

// ---------------------------------------------------------------------------
// Kernel 0 (fused): pack mask bits (all blocks) + E/maxT prep (block 0).
// ---------------------------------------------------------------------------
__global__ __launch_bounds__(128) void crf_prep_pack(const float* __restrict__ trans,
                                                     const int* __restrict__ mask,
                                                     float* __restrict__ E,
                                                     float* __restrict__ maxT,
                                                     unsigned* __restrict__ mbits) {
    const int b = blockIdx.x;
    const int tid = threadIdx.x;
    if (tid < 16) {
        unsigned bits = 0u;
        for (int k = 0; k < 32; ++k)
            bits |= (mask[b * TT + tid * 32 + k] ? 1u : 0u) << k;
        mbits[b * 16 + tid] = bits;
    }
    if (b == 0 && tid < CC) {
        float m = -INFINITY;
        for (int i = 0; i < CC; ++i) m = fmaxf(m, trans[i * CC + tid]);
        maxT[tid] = m;
        for (int i = 0; i < CC; ++i) E[i * CC + tid] = __expf(trans[i * CC + tid] - m);
    }
}

// ---------------------------------------------------------------------------
// Kernel 1: BIDIRECTIONAL halves, QUAD-split + DPP reduce — r24/r26 VERIFIED
// OPTIMUM (134.9us half), byte-identical. 3 waves/block; lane (g=l&3,
// jp=16v+(l>>2)) owns pair (2jp,2jp+1) over i-group [24g,24g+24). Per step:
// 12 broadcast ds_read_b64 (padded 26-float groups, banks {0,26,20,14}) +
// 24 pk_fma + quad_add DPP reduce (VALU) + 1 publish write + ONE
// lgkm+barrier. Renorm@8 via shfl+wsum. setprio(1) around matvec.
// Cost model: 1264 cyc/step = ~936 DS-issue + ~330 sync/skew (structural
// serial-dependence floor, not a HW roofline).
// ---------------------------------------------------------------------------
#define PKFMA_LO(A_, S_, E_) \
    asm("v_pk_fma_f32 %0, %1, %2, %0 op_sel:[0,0,0] op_sel_hi:[0,1,1]" \
        : "+v"(A_) : "v"(S_), "v"(E_))
#define PKFMA_HI(A_, S_, E_) \
    asm("v_pk_fma_f32 %0, %1, %2, %0 op_sel:[1,0,0] op_sel_hi:[1,1,1]" \
        : "+v"(A_) : "v"(S_), "v"(E_))

__device__ __forceinline__ float quad_add(float v) {
    int t = __builtin_amdgcn_update_dpp(0, __float_as_int(v), 0xB1, 0xF, 0xF, true);
    v += __int_as_float(t);
    t = __builtin_amdgcn_update_dpp(0, __float_as_int(v), 0x4E, 0xF, 0xF, true);
    return v + __int_as_float(t);
}

#define QMATVEC(PR_, ER_)                                                     \
    float2 a0={0.f,0.f}, a1={0.f,0.f}, a2={0.f,0.f}, a3={0.f,0.f};            \
    _Pragma("unroll")                                                         \
    for (int k_ = 0; k_ < 24; k_ += 4) {                                      \
        const float2 p0_ = *(const float2*)&pb[PR_][rb + k_];                 \
        const float2 p1_ = *(const float2*)&pb[PR_][rb + k_ + 2];             \
        PKFMA_LO(a0, p0_, ER_[k_]);                                           \
        PKFMA_HI(a1, p0_, ER_[k_ + 1]);                                       \
        PKFMA_LO(a2, p1_, ER_[k_ + 2]);                                       \
        PKFMA_HI(a3, p1_, ER_[k_ + 3]);                                       \
    }                                                                         \
    const float qx_ = quad_add((a0.x + a1.x) + (a2.x + a3.x));                \
    const float qy_ = quad_add((a0.y + a1.y) + (a2.y + a3.y));

#define RENORM_BLOCK(PX_, PY_)                                                \
    {                                                                         \
        float loc_ = (g == 0) ? (PX_ + PY_) : 0.f;                            \
        _Pragma("unroll")                                                     \
        for (int o_ = 32; o_; o_ >>= 1) loc_ += __shfl_xor(loc_, o_);         \
        if (l == 0) wsum[v] = loc_;                                           \
        asm volatile("s_waitcnt lgkmcnt(0)" ::: "memory");                    \
        __builtin_amdgcn_s_barrier();                                         \
        const float r_ = (wsum[0] + wsum[1]) + wsum[2];                       \
        const float inv_ = 1.0f / r_;                                         \
        PX_ *= inv_; PY_ *= inv_;                                             \
        S += (double)__logf(r_);                                              \
    }

#define FSTEP(PF_, K_, BIT_, REN_) do {                                       \
    const int sl_ = (K_) & 3;                                                 \
    const int pr_ = (K_) & 1;                                                 \
    const float2 ce_ = es[sl_];                                               \
    es[sl_] = *(const float2*)(PF_);                                          \
    const float scx_ = __expf(mTx + ce_.x);                                   \
    const float scy_ = __expf(mTy + ce_.y);                                   \
    __builtin_amdgcn_s_setprio(1);                                            \
    QMATVEC(pr_, ep2)                                                         \
    __builtin_amdgcn_s_setprio(0);                                            \
    if (BIT_) { px = qx_ * scx_; py = qy_ * scy_; }                           \
    if (REN_) RENORM_BLOCK(px, py)                                            \
    if (g == 0) *(float2*)&pb[pr_ ^ 1][pidx] = make_float2(px, py);           \
    asm volatile("s_waitcnt lgkmcnt(0)" ::: "memory");                        \
    __builtin_amdgcn_s_barrier();                                             \
} while (0)

#define BSTEP(PF_, SL_, PR_, BIT_, REN_) do {                                 \
    const float2 ce_ = es[SL_];                                               \
    es[SL_] = *(const float2*)(PF_);                                          \
    __builtin_amdgcn_s_setprio(1);                                            \
    QMATVEC(PR_, eb2)                                                         \
    __builtin_amdgcn_s_setprio(0);                                            \
    if (BIT_) { cx = qx_; cy = qy_; }                                         \
    if (REN_) RENORM_BLOCK(cx, cy)                                            \
    if (g == 0) *(float2*)&pb[(PR_) ^ 1][pidx] =                              \
        make_float2(__expf(mTx + ce_.x) * cx, __expf(mTy + ce_.y) * cy);      \
    asm volatile("s_waitcnt lgkmcnt(0)" ::: "memory");                        \
    __builtin_amdgcn_s_barrier();                                             \
} while (0)

__global__ __launch_bounds__(192, 1)
void crf_half(const float* __restrict__ emissions,
              const unsigned* __restrict__ mbits,
              const float* __restrict__ start_t,
              const float* __restrict__ end_t,
              const float* __restrict__ E,
              const float* __restrict__ maxT,
              float* __restrict__ pmid, float* __restrict__ cmid,
              double* __restrict__ Sf, double* __restrict__ Sb) {
    const int dir = blockIdx.x >> 9;      // 0 = forward half, 1 = backward half
    const int b = blockIdx.x & 511;
    const int v = threadIdx.x >> 6;       // wave 0..2
    const int l = threadIdx.x & 63;
    const int g = l & 3;                  // i-group [24g, 24g+24)
    const int jp = 16 * v + (l >> 2);     // owned output pair index (0..47)
    const int s0 = 2 * jp;                // owned states s0, s0+1
    const int rb = 26 * g;                // padded read base of own i-group
    const int pidx = 26 * (s0 / 24) + (s0 % 24);   // padded publish index

    __shared__ __align__(16) float pb[2][104];
    __shared__ float wsum[3];

    const float* ep = emissions + (size_t)b * TT * CC + s0;
    const float mTx = maxT[s0];
    const float mTy = maxT[s0 + 1];
    double S = 0.0;
    float2 es[4];

    if (dir == 0) {
        // ---------------- forward half: t = 1..255 ----------------
        float2 ep2[24];                    // (E[24g+k][s0], E[24g+k][s0+1])
#pragma unroll
        for (int k = 0; k < 24; ++k)
            ep2[k] = *(const float2*)(E + (size_t)(24 * g + k) * CC + s0);

        float px, py;
        {
            const float2 e0 = *(const float2*)ep;
            px = __expf(start_t[s0]     + e0.x);
            py = __expf(start_t[s0 + 1] + e0.y);
        }
        if (g == 0) *(float2*)&pb[1][pidx] = make_float2(px, py);
        asm volatile("s_waitcnt lgkmcnt(0)" ::: "memory");
        __builtin_amdgcn_s_barrier();

#pragma unroll
        for (int s = 1; s <= 4; ++s) es[s & 3] = *(const float2*)(ep + (size_t)s * CC);
        const float* pf = ep + (size_t)5 * CC;

        const unsigned wb0 = mbits[b * 16];
#pragma unroll
        for (int k = 1; k < 8; ++k) {
            FSTEP(pf, k, (wb0 >> k) & 1u, 0);
            pf += CC;
        }
        unsigned swc = wb0 >> 8;
        for (int sb = 1; sb < 32; ++sb) {
            const int sbn = sb + 1;
            const unsigned swn = mbits[b * 16 + (sbn >> 2)] >> ((sbn & 3) * 8);
#pragma unroll
            for (int k = 0; k < 8; ++k) {
                FSTEP(pf, k, (swc >> k) & 1u, k == 0);
                pf += CC;
            }
            swc = swn;
        }
        if (g == 0) *(float2*)&pmid[(size_t)b * CC + s0] = make_float2(px, py);
        if (threadIdx.x == 0) Sf[b] = S;
    } else {
        // ---------------- backward half: t = 511..256 ----------------
        float2 eb2[24];                    // (E[s0][24g+k], E[s0+1][24g+k])
#pragma unroll
        for (int k = 0; k < 24; ++k)
            eb2[k] = make_float2(E[(size_t)s0 * CC + 24 * g + k],
                                 E[(size_t)(s0 + 1) * CC + 24 * g + k]);

        float cx = __expf(end_t[s0]);
        float cy = __expf(end_t[s0 + 1]);
        {
            const float2 e511 = *(const float2*)(ep + (size_t)511 * CC);
            if (g == 0) *(float2*)&pb[0][pidx] =
                make_float2(__expf(mTx + e511.x) * cx, __expf(mTy + e511.y) * cy);
        }
        asm volatile("s_waitcnt lgkmcnt(0)" ::: "memory");
        __builtin_amdgcn_s_barrier();

#pragma unroll
        for (int s = 0; s < 4; ++s)
            es[(510 - s) & 3] = *(const float2*)(ep + (size_t)(510 - s) * CC);
        const float* pf = ep + (size_t)506 * CC;

        unsigned wv = mbits[b * 16 + 15] >> 24;
        for (int grp = 63; grp >= 32; --grp) {
            const int gn = grp - 1;
            const unsigned wn = mbits[b * 16 + (gn >> 2)] >> ((gn & 3) * 8);
#pragma unroll
            for (int k = 0; k < 8; ++k) {                // t = 8*grp + 7 - k
                BSTEP(pf, (6 - k) & 3, k & 1, (wv >> (7 - k)) & 1u, k == 7);
                pf -= CC;
            }
            wv = wn;
        }
        if (g == 0) *(float2*)&cmid[(size_t)b * CC + s0] = make_float2(cx, cy);
        if (threadIdx.x == 0) Sb[b] = S;
    }
}

// ---------------------------------------------------------------------------
// Kernel 2 (fused): joint likelihood + combine -> diff[b] = log_den - log_num
// ---------------------------------------------------------------------------
__global__ __launch_bounds__(256) void crf_joint_combine(const float* __restrict__ emissions,
                                                         const int* __restrict__ tags,
                                                         const int* __restrict__ mask,
                                                         const float* __restrict__ trans,
                                                         const float* __restrict__ start_t,
                                                         const float* __restrict__ end_t,
                                                         const float* __restrict__ pmid,
                                                         const float* __restrict__ cmid,
                                                         const double* __restrict__ Sf,
                                                         const double* __restrict__ Sb,
                                                         float* __restrict__ diff) {
    const int b = blockIdx.x;
    const int tid = threadIdx.x;
    // --- joint phase (all 256 threads) ---
    float s = 0.f;
    int mcount = 0;
    for (int t = tid; t < TT; t += 256) {
        int tg = tags[b * TT + t];
        float em = emissions[((size_t)b * TT + t) * CC + tg];
        int mk = mask[b * TT + t];
        mcount += mk;
        if (t == 0) {
            s += start_t[tg] + em;  // t=0 term unmasked in reference
        } else {
            int tp = tags[b * TT + t - 1];
            s += mk ? (trans[tp * CC + tg] + em) : 0.f;
        }
    }
    __shared__ float sred[4];
    __shared__ int mred[4];
#pragma unroll
    for (int off = 32; off; off >>= 1) {
        s += __shfl_xor(s, off);
        mcount += __shfl_xor(mcount, off);
    }
    if ((tid & 63) == 0) { sred[tid >> 6] = s; mred[tid >> 6] = mcount; }
    // --- combine phase (wave 0) ---
    float cv = 0.f;
    if (tid < 64) {
        if (tid < 48) {
            const float2 p2 = *(const float2*)&pmid[(size_t)b * CC + 2 * tid];
            const float2 c2 = *(const float2*)&cmid[(size_t)b * CC + 2 * tid];
            cv = p2.x * c2.x + p2.y * c2.y;
        }
#pragma unroll
        for (int off = 32; off; off >>= 1) cv += __shfl_xor(cv, off);
    }
    __syncthreads();
    if (tid == 0) {
        float tot = (sred[0] + sred[1]) + (sred[2] + sred[3]);
        int mt = (mred[0] + mred[1]) + (mred[2] + mred[3]);
        int last_tag = tags[b * TT + (mt - 1)];
        const float log_num = tot + end_t[last_tag];
        const float log_den = (float)(Sf[b] + Sb[b] + (double)__logf(cv));
        diff[b] = log_den - log_num;
    }
}

// ---------------------------------------------------------------------------
// Kernel 3: final mean(diff)
// ---------------------------------------------------------------------------
__global__ __launch_bounds__(512) void crf_final(const float* __restrict__ diff,
                                                 float* __restrict__ out) {
    const int tid = threadIdx.x;
    float d = diff[tid];
#pragma unroll
    for (int off = 32; off; off >>= 1) d += __shfl_xor(d, off);
    __shared__ float sred[8];
    if ((tid & 63) == 0) sred[tid >> 6] = d;
    __syncthreads();
    if (tid == 0) {
        float tot = 0.f;
        for (int w = 0; w < 8; ++w) tot += sred[w];
        out[0] = tot / (float)BB;
    }
}

extern "C" void kernel_launch(void* const* d_in, const int* in_sizes, int n_in,
                              void* d_out, int out_size, void* d_ws, size_t ws_size,
                              hipStream_t stream) {
    const float* emissions = (const float*)d_in[0];
    const int*   tags      = (const int*)d_in[1];
    const int*   mask      = (const int*)d_in[2];
    const float* trans     = (const float*)d_in[3];
    const float* start_t   = (const float*)d_in[4];
    const float* end_t     = (const float*)d_in[5];
    float* out = (float*)d_out;

    float*    ws      = (float*)d_ws;
    float*    E       = ws;                         // 9216 f
    float*    maxT    = ws + 9216;                  // 96 f
    float*    diff    = ws + 9312;                  // 512 f
    unsigned* mbits   = (unsigned*)(ws + 10336);    // 8192 u32
    float*    pmid    = ws + 18528;                 // 512*96 f
    float*    cmid    = ws + 67680;                 // 512*96 f
    double*   Sf      = (double*)(ws + 116832);     // 512 d (8B aligned)
    double*   Sb      = (double*)(ws + 117856);     // 512 d

    crf_prep_pack<<<BB, 128, 0, stream>>>(trans, mask, E, maxT, mbits);
    crf_half<<<2 * BB, 192, 0, stream>>>(emissions, mbits, start_t, end_t, E, maxT,
                                         pmid, cmid, Sf, Sb);
    crf_joint_combine<<<BB, 256, 0, stream>>>(emissions, tags, mask, trans, start_t,
                                              end_t, pmid, cmid, Sf, Sb, diff);
    crf_final<<<1, 512, 0, stream>>>(diff, out);
}

// Round 28
// 146.808 us; speedup vs baseline: 1.0530x; 1.0530x over previous
//
#include <hip/hip_runtime.h>
#include <math.h>

#define CC 96
#define BB 512
#define TT 512

// ---------------------------------------------------------------------------
// Kernel 0: column max of transitions and E[i][j] = exp(T[i][j]-maxT[j])
// ---------------------------------------------------------------------------
__global__ __launch_bounds__(128) void crf_prep(const float* __restrict__ trans,
                                                float* __restrict__ E,
                                                float* __restrict__ maxT) {
    int j = threadIdx.x;
    if (j < CC) {
        float m = -INFINITY;
        for (int i = 0; i < CC; ++i) m = fmaxf(m, trans[i * CC + j]);
        maxT[j] = m;
        for (int i = 0; i < CC; ++i) E[i * CC + j] = __expf(trans[i * CC + j] - m);
    }
}

// ---------------------------------------------------------------------------
// Kernel 0b: pack mask rows into bit-words (no per-step SMEM loads).
// ---------------------------------------------------------------------------
__global__ __launch_bounds__(64) void pack_mask(const int* __restrict__ mask,
                                                unsigned* __restrict__ mbits) {
    const int b = blockIdx.x;
    const int w = threadIdx.x;
    if (w < 16) {
        unsigned bits = 0u;
        for (int k = 0; k < 32; ++k)
            bits |= (mask[b * TT + w * 32 + k] ? 1u : 0u) << k;
        mbits[b * 16 + w] = bits;
    }
}

// ---------------------------------------------------------------------------
// Kernel 1: BIDIRECTIONAL halves, QUAD-split + DPP reduce — r24/r26 VERIFIED
// OPTIMUM (134.9us half / 147.0us total), restored after r27's kernel-fusion
// attempt perturbed crf_half's codegen (+9%, rule-#19 co-compilation noise).
// Structure: 3 waves/block, all 64 lanes active; lane (g=l&3, jp=16v+(l>>2))
// owns output pair (2jp,2jp+1) over i-group [24g,24g+24). Per step per wave:
// 12 broadcast ds_read_b64 (padded 26-float groups: addrs {0,26,52,78} ->
// banks {0,26,20,14}, conflict-free) + 24 pk_fma + 4-way reduce as TWO DPP
// quad_perm adds (VALU pipe, zero DS) + 1 publish ds_write (g==0) + ONE
// lgkm+barrier. Renorm every 8 steps via shfl+wsum. setprio(1) around the
// matvec (r23: -7%). Reduction tree == r14's (g0+g1)+(g2+g3).
// Cost model (fitted r17-r24): 1264 cyc/step = ~936 DS-issue (4 chains/CU x
// 39 DS x ~6cy) + ~330 sync/skew. Serial-dependence floor, not HW roofline.
// ---------------------------------------------------------------------------
#define PKFMA_LO(A_, S_, E_) \
    asm("v_pk_fma_f32 %0, %1, %2, %0 op_sel:[0,0,0] op_sel_hi:[0,1,1]" \
        : "+v"(A_) : "v"(S_), "v"(E_))
#define PKFMA_HI(A_, S_, E_) \
    asm("v_pk_fma_f32 %0, %1, %2, %0 op_sel:[1,0,0] op_sel_hi:[1,1,1]" \
        : "+v"(A_) : "v"(S_), "v"(E_))

__device__ __forceinline__ float quad_add(float v) {
    // v += lane^1;  v += lane^2  (quad_perm DPP, VALU pipe)
    int t = __builtin_amdgcn_update_dpp(0, __float_as_int(v), 0xB1, 0xF, 0xF, true);
    v += __int_as_float(t);
    t = __builtin_amdgcn_update_dpp(0, __float_as_int(v), 0x4E, 0xF, 0xF, true);
    return v + __int_as_float(t);
}

// matvec over own i-group: 12 b64 broadcast reads + 24 pk_fma -> quad reduce
#define QMATVEC(PR_, ER_)                                                     \
    float2 a0={0.f,0.f}, a1={0.f,0.f}, a2={0.f,0.f}, a3={0.f,0.f};            \
    _Pragma("unroll")                                                         \
    for (int k_ = 0; k_ < 24; k_ += 4) {                                      \
        const float2 p0_ = *(const float2*)&pb[PR_][rb + k_];                 \
        const float2 p1_ = *(const float2*)&pb[PR_][rb + k_ + 2];             \
        PKFMA_LO(a0, p0_, ER_[k_]);                                           \
        PKFMA_HI(a1, p0_, ER_[k_ + 1]);                                       \
        PKFMA_LO(a2, p1_, ER_[k_ + 2]);                                       \
        PKFMA_HI(a3, p1_, ER_[k_ + 3]);                                       \
    }                                                                         \
    const float qx_ = quad_add((a0.x + a1.x) + (a2.x + a3.x));                \
    const float qy_ = quad_add((a0.y + a1.y) + (a2.y + a3.y));

#define RENORM_BLOCK(PX_, PY_)                                                \
    {                                                                         \
        float loc_ = (g == 0) ? (PX_ + PY_) : 0.f;                            \
        _Pragma("unroll")                                                     \
        for (int o_ = 32; o_; o_ >>= 1) loc_ += __shfl_xor(loc_, o_);         \
        if (l == 0) wsum[v] = loc_;                                           \
        asm volatile("s_waitcnt lgkmcnt(0)" ::: "memory");                    \
        __builtin_amdgcn_s_barrier();                                         \
        const float r_ = (wsum[0] + wsum[1]) + wsum[2];                       \
        const float inv_ = 1.0f / r_;                                         \
        PX_ *= inv_; PY_ *= inv_;                                             \
        S += (double)__logf(r_);                                              \
    }

// forward step: consume em_t, quad-matvec p.E, scale-after, publish
#define FSTEP(PF_, K_, BIT_, REN_) do {                                       \
    const int sl_ = (K_) & 3;                                                 \
    const int pr_ = (K_) & 1;                                                 \
    const float2 ce_ = es[sl_];                                               \
    es[sl_] = *(const float2*)(PF_);                                          \
    const float scx_ = __expf(mTx + ce_.x);                                   \
    const float scy_ = __expf(mTy + ce_.y);                                   \
    __builtin_amdgcn_s_setprio(1);                                            \
    QMATVEC(pr_, ep2)                                                         \
    __builtin_amdgcn_s_setprio(0);                                            \
    if (BIT_) { px = qx_ * scx_; py = qy_ * scy_; }                           \
    if (REN_) RENORM_BLOCK(px, py)                                            \
    if (g == 0) *(float2*)&pb[pr_ ^ 1][pidx] = make_float2(px, py);           \
    asm volatile("s_waitcnt lgkmcnt(0)" ::: "memory");                        \
    __builtin_amdgcn_s_barrier();                                             \
} while (0)

// backward step: quad-matvec E.u (u = sc (.) c published), masked update,
// publish next u scaled-before. Same sync structure.
#define BSTEP(PF_, SL_, PR_, BIT_, REN_) do {                                 \
    const float2 ce_ = es[SL_];                                               \
    es[SL_] = *(const float2*)(PF_);                                          \
    __builtin_amdgcn_s_setprio(1);                                            \
    QMATVEC(PR_, eb2)                                                         \
    __builtin_amdgcn_s_setprio(0);                                            \
    if (BIT_) { cx = qx_; cy = qy_; }                                         \
    if (REN_) RENORM_BLOCK(cx, cy)                                            \
    if (g == 0) *(float2*)&pb[(PR_) ^ 1][pidx] =                              \
        make_float2(__expf(mTx + ce_.x) * cx, __expf(mTy + ce_.y) * cy);      \
    asm volatile("s_waitcnt lgkmcnt(0)" ::: "memory");                        \
    __builtin_amdgcn_s_barrier();                                             \
} while (0)

__global__ __launch_bounds__(192, 1)
void crf_half(const float* __restrict__ emissions,
              const unsigned* __restrict__ mbits,
              const float* __restrict__ start_t,
              const float* __restrict__ end_t,
              const float* __restrict__ E,
              const float* __restrict__ maxT,
              float* __restrict__ pmid, float* __restrict__ cmid,
              double* __restrict__ Sf, double* __restrict__ Sb) {
    const int dir = blockIdx.x >> 9;      // 0 = forward half, 1 = backward half
    const int b = blockIdx.x & 511;
    const int v = threadIdx.x >> 6;       // wave 0..2
    const int l = threadIdx.x & 63;
    const int g = l & 3;                  // i-group [24g, 24g+24)
    const int jp = 16 * v + (l >> 2);     // owned output pair index (0..47)
    const int s0 = 2 * jp;                // owned states s0, s0+1
    const int rb = 26 * g;                // padded read base of own i-group
    const int pidx = 26 * (s0 / 24) + (s0 % 24);   // padded publish index

    // padded state vector: 4 groups of 24 + 2 pad -> group bases {0,26,52,78}
    __shared__ __align__(16) float pb[2][104];
    __shared__ float wsum[3];

    const float* ep = emissions + (size_t)b * TT * CC + s0;
    const float mTx = maxT[s0];
    const float mTy = maxT[s0 + 1];
    double S = 0.0;
    float2 es[4];

    if (dir == 0) {
        // ---------------- forward half: t = 1..255 ----------------
        float2 ep2[24];                    // (E[24g+k][s0], E[24g+k][s0+1])
#pragma unroll
        for (int k = 0; k < 24; ++k)
            ep2[k] = *(const float2*)(E + (size_t)(24 * g + k) * CC + s0);

        float px, py;
        {
            const float2 e0 = *(const float2*)ep;
            px = __expf(start_t[s0]     + e0.x);
            py = __expf(start_t[s0 + 1] + e0.y);
        }
        if (g == 0) *(float2*)&pb[1][pidx] = make_float2(px, py);
        asm volatile("s_waitcnt lgkmcnt(0)" ::: "memory");
        __builtin_amdgcn_s_barrier();      // init publish visible cross-wave

#pragma unroll
        for (int s = 1; s <= 4; ++s) es[s & 3] = *(const float2*)(ep + (size_t)s * CC);
        const float* pf = ep + (size_t)5 * CC;

        const unsigned wb0 = mbits[b * 16];
#pragma unroll
        for (int k = 1; k < 8; ++k) {
            FSTEP(pf, k, (wb0 >> k) & 1u, 0);
            pf += CC;
        }
        unsigned swc = wb0 >> 8;
        for (int sb = 1; sb < 32; ++sb) {
            const int sbn = sb + 1;
            const unsigned swn = mbits[b * 16 + (sbn >> 2)] >> ((sbn & 3) * 8);
#pragma unroll
            for (int k = 0; k < 8; ++k) {
                FSTEP(pf, k, (swc >> k) & 1u, k == 0);
                pf += CC;
            }
            swc = swn;
        }
        // state now = p_255 (renormalized), S = log-scale
        if (g == 0) *(float2*)&pmid[(size_t)b * CC + s0] = make_float2(px, py);
        if (threadIdx.x == 0) Sf[b] = S;
    } else {
        // ---------------- backward half: t = 511..256 ----------------
        float2 eb2[24];                    // (E[s0][24g+k], E[s0+1][24g+k])
#pragma unroll
        for (int k = 0; k < 24; ++k)
            eb2[k] = make_float2(E[(size_t)s0 * CC + 24 * g + k],
                                 E[(size_t)(s0 + 1) * CC + 24 * g + k]);

        float cx = __expf(end_t[s0]);
        float cy = __expf(end_t[s0 + 1]);
        {   // initial publish: u_511 = sc_511 (.) c_511, into parity 0
            const float2 e511 = *(const float2*)(ep + (size_t)511 * CC);
            if (g == 0) *(float2*)&pb[0][pidx] =
                make_float2(__expf(mTx + e511.x) * cx, __expf(mTy + e511.y) * cy);
        }
        asm volatile("s_waitcnt lgkmcnt(0)" ::: "memory");
        __builtin_amdgcn_s_barrier();      // init publish visible cross-wave

        // prefetch em stream m = t-1 descending: m = 510..507
#pragma unroll
        for (int s = 0; s < 4; ++s)
            es[(510 - s) & 3] = *(const float2*)(ep + (size_t)(510 - s) * CC);
        const float* pf = ep + (size_t)506 * CC;

        unsigned wv = mbits[b * 16 + 15] >> 24;          // bits t=504..511
        for (int grp = 63; grp >= 32; --grp) {
            const int gn = grp - 1;
            const unsigned wn = mbits[b * 16 + (gn >> 2)] >> ((gn & 3) * 8);
#pragma unroll
            for (int k = 0; k < 8; ++k) {                // t = 8*grp + 7 - k
                BSTEP(pf, (6 - k) & 3, k & 1, (wv >> (7 - k)) & 1u, k == 7);
                pf -= CC;
            }
            wv = wn;
        }
        // state now = c_255 (renormalized), S = log-scale
        if (g == 0) *(float2*)&cmid[(size_t)b * CC + s0] = make_float2(cx, cy);
        if (threadIdx.x == 0) Sb[b] = S;
    }
}

// ---------------------------------------------------------------------------
// Kernel 1b: combine halves — log_den[b] = Sf + Sb + log(sum_j p[j]*c[j])
// ---------------------------------------------------------------------------
__global__ __launch_bounds__(64) void crf_combine(const float* __restrict__ pmid,
                                                  const float* __restrict__ cmid,
                                                  const double* __restrict__ Sf,
                                                  const double* __restrict__ Sb,
                                                  float* __restrict__ log_den) {
    const int b = blockIdx.x;
    const int l = threadIdx.x;
    float v = 0.f;
    if (l < 48) {
        const float2 p2 = *(const float2*)&pmid[(size_t)b * CC + 2 * l];
        const float2 c2 = *(const float2*)&cmid[(size_t)b * CC + 2 * l];
        v = p2.x * c2.x + p2.y * c2.y;
    }
#pragma unroll
    for (int off = 32; off; off >>= 1) v += __shfl_xor(v, off);
    if (l == 0) log_den[b] = (float)(Sf[b] + Sb[b] + (double)__logf(v));
}

// ---------------------------------------------------------------------------
// Kernel 2: joint likelihood (numerator) — one block per batch.
// ---------------------------------------------------------------------------
__global__ __launch_bounds__(256) void crf_joint(const float* __restrict__ emissions,
                                                 const int* __restrict__ tags,
                                                 const int* __restrict__ mask,
                                                 const float* __restrict__ trans,
                                                 const float* __restrict__ start_t,
                                                 const float* __restrict__ end_t,
                                                 float* __restrict__ log_num) {
    const int b = blockIdx.x;
    const int tid = threadIdx.x;
    float s = 0.f;
    int mcount = 0;
    for (int t = tid; t < TT; t += 256) {
        int tg = tags[b * TT + t];
        float em = emissions[((size_t)b * TT + t) * CC + tg];
        int mk = mask[b * TT + t];
        mcount += mk;
        if (t == 0) {
            s += start_t[tg] + em;  // t=0 term unmasked in reference
        } else {
            int tp = tags[b * TT + t - 1];
            s += mk ? (trans[tp * CC + tg] + em) : 0.f;
        }
    }
    __shared__ float sred[4];
    __shared__ int mred[4];
#pragma unroll
    for (int off = 32; off; off >>= 1) {
        s += __shfl_xor(s, off);
        mcount += __shfl_xor(mcount, off);
    }
    if ((tid & 63) == 0) { sred[tid >> 6] = s; mred[tid >> 6] = mcount; }
    __syncthreads();
    if (tid == 0) {
        float tot = (sred[0] + sred[1]) + (sred[2] + sred[3]);
        int mt = (mred[0] + mred[1]) + (mred[2] + mred[3]);
        int last_tag = tags[b * TT + (mt - 1)];
        log_num[b] = tot + end_t[last_tag];
    }
}

// ---------------------------------------------------------------------------
// Kernel 3: final mean(log_den - log_num)
// ---------------------------------------------------------------------------
__global__ __launch_bounds__(512) void crf_final(const float* __restrict__ log_den,
                                                 const float* __restrict__ log_num,
                                                 float* __restrict__ out) {
    const int tid = threadIdx.x;
    float d = log_den[tid] - log_num[tid];
#pragma unroll
    for (int off = 32; off; off >>= 1) d += __shfl_xor(d, off);
    __shared__ float sred[8];
    if ((tid & 63) == 0) sred[tid >> 6] = d;
    __syncthreads();
    if (tid == 0) {
        float tot = 0.f;
        for (int w = 0; w < 8; ++w) tot += sred[w];
        out[0] = tot / (float)BB;
    }
}

extern "C" void kernel_launch(void* const* d_in, const int* in_sizes, int n_in,
                              void* d_out, int out_size, void* d_ws, size_t ws_size,
                              hipStream_t stream) {
    const float* emissions = (const float*)d_in[0];
    const int*   tags      = (const int*)d_in[1];
    const int*   mask      = (const int*)d_in[2];
    const float* trans     = (const float*)d_in[3];
    const float* start_t   = (const float*)d_in[4];
    const float* end_t     = (const float*)d_in[5];
    float* out = (float*)d_out;

    float*    ws      = (float*)d_ws;
    float*    E       = ws;                         // 9216 f
    float*    maxT    = ws + 9216;                  // 96 f
    float*    log_den = ws + 9312;                  // 512 f
    float*    log_num = ws + 9824;                  // 512 f
    unsigned* mbits   = (unsigned*)(ws + 10336);    // 8192 u32
    float*    pmid    = ws + 18528;                 // 512*96 f
    float*    cmid    = ws + 67680;                 // 512*96 f
    double*   Sf      = (double*)(ws + 116832);     // 512 d (8B aligned)
    double*   Sb      = (double*)(ws + 117856);     // 512 d

    crf_prep<<<1, 128, 0, stream>>>(trans, E, maxT);
    pack_mask<<<BB, 64, 0, stream>>>(mask, mbits);
    crf_half<<<2 * BB, 192, 0, stream>>>(emissions, mbits, start_t, end_t, E, maxT,
                                         pmid, cmid, Sf, Sb);
    crf_combine<<<BB, 64, 0, stream>>>(pmid, cmid, Sf, Sb, log_den);
    crf_joint<<<BB, 256, 0, stream>>>(emissions, tags, mask, trans, start_t, end_t, log_num);
    crf_final<<<1, 512, 0, stream>>>(log_den, log_num, out);
}